// Round 1
// baseline (431.311 us; speedup 1.0000x reference)
//
#include <hip/hip_runtime.h>
#include <stdint.h>

#define SEQ 2048
#define HIDDEN 1024
#define NHEADS 16
#define HDIM 64
#define MTOT 8192  // B*SEQ

// 1/sqrt(HDIM) * log2(e), folded into wq/bq so attn does exp2(S) directly
#define C1SCALE 0.1803368801111437f

typedef __bf16 bf16x8 __attribute__((ext_vector_type(8)));
typedef unsigned short u16x8 __attribute__((ext_vector_type(8)));
typedef short s16x4 __attribute__((ext_vector_type(4)));
typedef unsigned int u32x4 __attribute__((ext_vector_type(4)));
typedef float f32x4 __attribute__((ext_vector_type(4)));

#define GAS __attribute__((address_space(1)))
#define LAS __attribute__((address_space(3)))

__device__ __forceinline__ unsigned short bf16_rne(float f) {
  union { float f; unsigned int u; } v; v.f = f;
  return (unsigned short)((v.u + 0x7fffu + ((v.u >> 16) & 1u)) >> 16);
}

// pack 2 f32 -> 2 bf16 in one dword: round-half-up adds + one v_perm_b32
__device__ __forceinline__ unsigned int pk2(float lo, float hi) {
  unsigned int a = __builtin_bit_cast(unsigned int, hi) + 0x8000u;  // high short
  unsigned int b = __builtin_bit_cast(unsigned int, lo) + 0x8000u;  // low short
  return __builtin_amdgcn_perm(a, b, 0x07060302u);
}

__device__ __forceinline__ s16x4 pack4_bf16(float a, float b, float c, float d) {
  s16x4 r;
  r[0] = (short)bf16_rne(a); r[1] = (short)bf16_rne(b);
  r[2] = (short)bf16_rne(c); r[3] = (short)bf16_rne(d);
  return r;
}

__device__ __forceinline__ void gload_lds16(const unsigned short* g, unsigned short* l) {
  __builtin_amdgcn_global_load_lds((GAS void*)(unsigned short*)g, (LAS void*)l, 16, 0, 0);
}

// ---------------- fused fp32 -> bf16 conversions ---------------------------
__global__ __launch_bounds__(256) void cvt3(const float* __restrict__ a,
                                            const float* __restrict__ b,
                                            const float* __restrict__ c,
                                            unsigned short* __restrict__ out,
                                            int perSeg) {
  const int seg = blockIdx.y;
  const float* in = seg == 0 ? a : (seg == 1 ? b : c);
  int i = blockIdx.x * 256 + threadIdx.x;
  float4 v = ((const float4*)in)[i];
  ushort4 o;
  o.x = bf16_rne(v.x); o.y = bf16_rne(v.y);
  o.z = bf16_rne(v.z); o.w = bf16_rne(v.w);
  ((ushort4*)(out + (size_t)seg * perSeg))[i] = o;
}

// seg 0 (wq) is pre-scaled by C1SCALE (softmax scale folded into Q projection)
__global__ __launch_bounds__(256) void cvt4(const float* __restrict__ a,
                                            const float* __restrict__ b,
                                            const float* __restrict__ c,
                                            const float* __restrict__ d,
                                            unsigned short* __restrict__ out,
                                            int perSeg) {
  const int seg = blockIdx.y;
  const float* in = seg == 0 ? a : (seg == 1 ? b : (seg == 2 ? c : d));
  const float sc = (seg == 0) ? C1SCALE : 1.0f;
  int i = blockIdx.x * 256 + threadIdx.x;
  float4 v = ((const float4*)in)[i];
  ushort4 o;
  o.x = bf16_rne(v.x * sc); o.y = bf16_rne(v.y * sc);
  o.z = bf16_rne(v.z * sc); o.w = bf16_rne(v.w * sc);
  ((ushort4*)(out + (size_t)seg * perSeg))[i] = o;
}

// ---------------- fused QKV GEMM -------------------------------------------
__global__ __launch_bounds__(256) void gemm_qkv(const unsigned short* __restrict__ Xq,
                                                const unsigned short* __restrict__ Xk,
                                                const unsigned short* __restrict__ Xv,
                                                const unsigned short* __restrict__ W,
                                                const float* __restrict__ bq,
                                                const float* __restrict__ bk,
                                                const float* __restrict__ bv,
                                                unsigned short* __restrict__ Qb,
                                                unsigned short* __restrict__ Kb,
                                                unsigned short* __restrict__ Vb) {
  __shared__ unsigned short As[128 * 32];
  __shared__ unsigned short Bs[128 * 32];
  const int tid = threadIdx.x;
  const int lane = tid & 63, w = tid >> 6;
  const int quad = lane >> 4, ln = lane & 15;
  const int wm = w & 1, wn = w >> 1;
  const int mBase = blockIdx.y * 128, nBase = blockIdx.x * 128;
  const int seg = blockIdx.x >> 3;
  const unsigned short* A = seg == 0 ? Xq : (seg == 1 ? Xk : Xv);
  const float* bias = seg == 0 ? bq : (seg == 1 ? bk : bv);
  const float bscale = seg == 0 ? C1SCALE : 1.0f;
  unsigned short* outp = seg == 0 ? Qb : (seg == 1 ? Kb : Vb);
  const int K = HIDDEN;

  f32x4 acc[4][4];
  f32x4 zero = {0.f, 0.f, 0.f, 0.f};
#pragma unroll
  for (int i = 0; i < 4; i++)
#pragma unroll
    for (int j = 0; j < 4; j++) acc[i][j] = zero;

  const int e0 = tid * 8;
  const int e1 = (256 + tid) * 8;
  const int r0 = e0 >> 5, c0 = e0 & 31;
  const int r1 = e1 >> 5, c1 = e1 & 31;
  const unsigned short* Ap0 = A + (size_t)(mBase + r0) * K + c0;
  const unsigned short* Ap1 = A + (size_t)(mBase + r1) * K + c1;
  const unsigned short* Wp0 = W + (size_t)(nBase + r0) * K + c0;
  const unsigned short* Wp1 = W + (size_t)(nBase + r1) * K + c1;

  for (int k0 = 0; k0 < K; k0 += 32) {
    gload_lds16(Ap0 + k0, &As[e0]);
    gload_lds16(Ap1 + k0, &As[e1]);
    gload_lds16(Wp0 + k0, &Bs[e0]);
    gload_lds16(Wp1 + k0, &Bs[e1]);
    __syncthreads();
    u16x8 af[4], bfr[4];
#pragma unroll
    for (int mi = 0; mi < 4; mi++)
      af[mi] = *(const u16x8*)&As[(wm * 64 + mi * 16 + ln) * 32 + quad * 8];
#pragma unroll
    for (int ni = 0; ni < 4; ni++)
      bfr[ni] = *(const u16x8*)&Bs[(wn * 64 + ni * 16 + ln) * 32 + quad * 8];
#pragma unroll
    for (int mi = 0; mi < 4; mi++)
#pragma unroll
      for (int ni = 0; ni < 4; ni++)
        acc[mi][ni] = __builtin_amdgcn_mfma_f32_16x16x32_bf16(
            __builtin_bit_cast(bf16x8, af[mi]), __builtin_bit_cast(bf16x8, bfr[ni]),
            acc[mi][ni], 0, 0, 0);
    __syncthreads();
  }

#pragma unroll
  for (int ni = 0; ni < 4; ni++) {
    const int colg = nBase + wn * 64 + ni * 16 + ln;
    const int col = colg & 1023;
    const float bvv = bias[col] * bscale;
#pragma unroll
    for (int mi = 0; mi < 4; mi++) {
      const int row = mBase + wm * 64 + mi * 16 + quad * 4;
#pragma unroll
      for (int r = 0; r < 4; r++)
        outp[(size_t)(row + r) * HIDDEN + col] = bf16_rne(acc[mi][ni][r] + bvv);
    }
  }
}

// ---------------- final GEMM (fp32 out) ------------------------------------
__global__ __launch_bounds__(256) void gemm_f(const unsigned short* __restrict__ A,
                                              const unsigned short* __restrict__ W,
                                              const float* __restrict__ bias,
                                              float* __restrict__ Cv) {
  __shared__ unsigned short As[128 * 32];
  __shared__ unsigned short Bs[128 * 32];
  const int tid = threadIdx.x;
  const int lane = tid & 63, w = tid >> 6;
  const int quad = lane >> 4, ln = lane & 15;
  const int wm = w & 1, wn = w >> 1;
  const int mBase = blockIdx.y * 128, nBase = blockIdx.x * 128;
  const int K = HIDDEN, N = HIDDEN;

  f32x4 acc[4][4];
  f32x4 zero = {0.f, 0.f, 0.f, 0.f};
#pragma unroll
  for (int i = 0; i < 4; i++)
#pragma unroll
    for (int j = 0; j < 4; j++) acc[i][j] = zero;

  const int e0 = tid * 8;
  const int e1 = (256 + tid) * 8;
  const int r0 = e0 >> 5, c0 = e0 & 31;
  const int r1 = e1 >> 5, c1 = e1 & 31;
  const unsigned short* Ap0 = A + (size_t)(mBase + r0) * K + c0;
  const unsigned short* Ap1 = A + (size_t)(mBase + r1) * K + c1;
  const unsigned short* Wp0 = W + (size_t)(nBase + r0) * K + c0;
  const unsigned short* Wp1 = W + (size_t)(nBase + r1) * K + c1;

  for (int k0 = 0; k0 < K; k0 += 32) {
    gload_lds16(Ap0 + k0, &As[e0]);
    gload_lds16(Ap1 + k0, &As[e1]);
    gload_lds16(Wp0 + k0, &Bs[e0]);
    gload_lds16(Wp1 + k0, &Bs[e1]);
    __syncthreads();
    u16x8 af[4], bfr[4];
#pragma unroll
    for (int mi = 0; mi < 4; mi++)
      af[mi] = *(const u16x8*)&As[(wm * 64 + mi * 16 + ln) * 32 + quad * 8];
#pragma unroll
    for (int ni = 0; ni < 4; ni++)
      bfr[ni] = *(const u16x8*)&Bs[(wn * 64 + ni * 16 + ln) * 32 + quad * 8];
#pragma unroll
    for (int mi = 0; mi < 4; mi++)
#pragma unroll
      for (int ni = 0; ni < 4; ni++)
        acc[mi][ni] = __builtin_amdgcn_mfma_f32_16x16x32_bf16(
            __builtin_bit_cast(bf16x8, af[mi]), __builtin_bit_cast(bf16x8, bfr[ni]),
            acc[mi][ni], 0, 0, 0);
    __syncthreads();
  }

#pragma unroll
  for (int ni = 0; ni < 4; ni++) {
    const int col = nBase + wn * 64 + ni * 16 + ln;
    const float bvv = bias[col];
#pragma unroll
    for (int mi = 0; mi < 4; mi++) {
      const int row = mBase + wm * 64 + mi * 16 + quad * 4;
#pragma unroll
      for (int r = 0; r < 4; r++)
        Cv[(size_t)(row + r) * N + col] = acc[mi][ni][r] + bvv;
    }
  }
}

// ---------------- V transpose: fragment-linear A-frags for register PV -----
// Output layout per tile t = bh*16+kt (8192 elems):
//   frag f = g*4+mtd (g: 32-key group, mtd: 16-d block), 512 elems each.
//   Within frag: lane (quad,ln) holds u16x8 at f*512 + lane*8, element j =
//   V[key = g*32 + (j>>2)*16 + quad*4 + (j&3)][d = mtd*16 + ln]
//   (key permutation matches P's B-fragment layout from the swapped QK^T).
// Each wave-load in attn is 1024 contiguous bytes -> perfectly coalesced.
__global__ __launch_bounds__(256) void transpose_v(const unsigned short* __restrict__ Vb,
                                                   unsigned short* __restrict__ Vt) {
  __shared__ unsigned short L[128 * 90];
  const int t = blockIdx.x;  // 1024 tiles
  const int bh = t >> 4, kt = t & 15;
  const int b = bh >> 4, h = bh & 15;
  const int tid = threadIdx.x;
  {
    const int key = tid >> 1, hf = tid & 1;
    const unsigned short* src =
        Vb + ((size_t)(b * SEQ + kt * 128 + key)) * HIDDEN + h * HDIM + hf * 32;
    u16x8 a0 = *(const u16x8*)(src);
    u16x8 a1 = *(const u16x8*)(src + 8);
    u16x8 a2 = *(const u16x8*)(src + 16);
    u16x8 a3 = *(const u16x8*)(src + 24);
    unsigned short* dst = &L[key * 90 + hf * 32];
    *(u16x8*)(dst) = a0;
    *(u16x8*)(dst + 8) = a1;
    *(u16x8*)(dst + 16) = a2;
    *(u16x8*)(dst + 24) = a3;
  }
  __syncthreads();
  const int lane = tid & 63, w = tid >> 6;
  const int quad = lane >> 4, ln = lane & 15;
  unsigned short* out = Vt + (size_t)t * 8192;
#pragma unroll
  for (int gg = 0; gg < 4; gg++) {
    const int f = w * 4 + gg;
    const int g = f >> 2, mtd = f & 3;
    u16x8 v;
#pragma unroll
    for (int j = 0; j < 8; j++) {
      const int key = g * 32 + (j >> 2) * 16 + quad * 4 + (j & 3);
      v[j] = L[key * 90 + mtd * 16 + ln];
    }
    *(u16x8*)(out + f * 512 + lane * 8) = v;
  }
}

// ---------------- flash attention v6: LDS-free, barrier-free ---------------
// Q pre-scaled by C1SCALE upstream -> P = exp2(S) directly.
// No __shared__ at all: V comes from L2 as per-wave register A-fragments
// (fragment-linear Vt layout, coalesced 1 KiB wave loads, issued one full
// QK+softmax phase ahead of their PV use). K: depth-2 register ring
// (refill distance = 2 half-phases ~300cy, covers L2 latency).
// Denominator via ones-fragment MFMA (replaces per-lane VALU accumulation
// and the final cross-lane shuffle; consistent with bf16-rounded P in the
// numerator). No barriers -> all 16 waves/CU free-run; compiler emits only
// counted vmcnt waits on real dataflow. VGPR budget <=128 so all 4
// blocks/CU stay resident (grid = 1024 blocks exactly).
__global__ __launch_bounds__(256, 4) void attn6(const unsigned short* __restrict__ Q,
                                                const unsigned short* __restrict__ K,
                                                const unsigned short* __restrict__ Vt,
                                                unsigned short* __restrict__ X) {
  const int tid = threadIdx.x, lane = tid & 63, w = tid >> 6;
  const int quad = lane >> 4, ln = lane & 15;
  const int bh = blockIdx.x, b = bh >> 4, h = bh & 15;
  const size_t base = (size_t)b * SEQ * HIDDEN + (size_t)h * HDIM;
  const unsigned short* Qh = Q + base;
  const unsigned short* Kh = K + base;
  const unsigned short* vtile = Vt + (size_t)bh * 16 * 8192;
  const int qw = blockIdx.y * 128 + w * 32;

  // resident Q B-frags: B[k=d=kk2*32+quad*8+j][n=q=nt*16+ln]
  u16x8 qf[2][2];
#pragma unroll
  for (int nt = 0; nt < 2; nt++)
#pragma unroll
    for (int kk2 = 0; kk2 < 2; kk2++)
      qf[nt][kk2] = *(const u16x8*)(Qh + (size_t)(qw + nt * 16 + ln) * HIDDEN + kk2 * 32 + quad * 8);

  f32x4 o[4][2];
  f32x4 zero = {0.f, 0.f, 0.f, 0.f};
#pragma unroll
  for (int mtd = 0; mtd < 4; mtd++)
#pragma unroll
    for (int nt = 0; nt < 2; nt++) o[mtd][nt] = zero;
  f32x4 l2[2] = {zero, zero};

  u16x8 onesf;
#pragma unroll
  for (int j = 0; j < 8; j++) onesf[j] = 0x3F80;  // bf16 1.0

  const unsigned short* Kl = Kh + (size_t)ln * HIDDEN + quad * 8;

  // K prefetch ring, depth 2: slot = seq & 1, seq = kt*8 + mt
  u16x8 kp[2][2];
  kp[0][0] = *(const u16x8*)(Kl);
  kp[0][1] = *(const u16x8*)(Kl + 32);
  kp[1][0] = *(const u16x8*)(Kl + 16 * HIDDEN);
  kp[1][1] = *(const u16x8*)(Kl + 16 * HIDDEN + 32);

  for (int kt = 0; kt < 16; ++kt) {
#pragma unroll
    for (int g = 0; g < 4; g++) {
      // V A-frags for this 32-key group: issued here, consumed after QK+exp2
      u16x8 vp[4];
#pragma unroll
      for (int mtd = 0; mtd < 4; mtd++)
        vp[mtd] = *(const u16x8*)(vtile + kt * 8192 + (g * 4 + mtd) * 512 + lane * 8);

      u32x4 P[2];
#pragma unroll
      for (int half = 0; half < 2; half++) {
        const int mt = 2 * g + half;
        const int slot = mt & 1;
        f32x4 s0 = zero, s1 = zero;
        __builtin_amdgcn_s_setprio(1);
        s0 = __builtin_amdgcn_mfma_f32_16x16x32_bf16(
            __builtin_bit_cast(bf16x8, kp[slot][0]), __builtin_bit_cast(bf16x8, qf[0][0]), s0, 0, 0, 0);
        s0 = __builtin_amdgcn_mfma_f32_16x16x32_bf16(
            __builtin_bit_cast(bf16x8, kp[slot][1]), __builtin_bit_cast(bf16x8, qf[0][1]), s0, 0, 0, 0);
        s1 = __builtin_amdgcn_mfma_f32_16x16x32_bf16(
            __builtin_bit_cast(bf16x8, kp[slot][0]), __builtin_bit_cast(bf16x8, qf[1][0]), s1, 0, 0, 0);
        s1 = __builtin_amdgcn_mfma_f32_16x16x32_bf16(
            __builtin_bit_cast(bf16x8, kp[slot][1]), __builtin_bit_cast(bf16x8, qf[1][1]), s1, 0, 0, 0);
        __builtin_amdgcn_s_setprio(0);
        // refill slot with seq+2 (same kt or rolls into kt+1)
        const int nxt = kt * 8 + mt + 2;
        if (nxt < 128) {
          const unsigned short* ka = Kl + (size_t)nxt * 16 * HIDDEN;
          kp[slot][0] = *(const u16x8*)(ka);
          kp[slot][1] = *(const u16x8*)(ka + 32);
        }
        float e0[4], e1[4];
#pragma unroll
        for (int r = 0; r < 4; r++) {
          e0[r] = __builtin_exp2f(s0[r]);
          e1[r] = __builtin_exp2f(s1[r]);
        }
        if (half == 0) {
          P[0][0] = pk2(e0[0], e0[1]); P[0][1] = pk2(e0[2], e0[3]);
          P[1][0] = pk2(e1[0], e1[1]); P[1][1] = pk2(e1[2], e1[3]);
        } else {
          P[0][2] = pk2(e0[0], e0[1]); P[0][3] = pk2(e0[2], e0[3]);
          P[1][2] = pk2(e1[0], e1[1]); P[1][3] = pk2(e1[2], e1[3]);
        }
      }
      // PV + denominator for this 32-key group
      __builtin_amdgcn_s_setprio(1);
#pragma unroll
      for (int nt = 0; nt < 2; nt++) {
        bf16x8 pb = __builtin_bit_cast(bf16x8, P[nt]);
        l2[nt] = __builtin_amdgcn_mfma_f32_16x16x32_bf16(
            __builtin_bit_cast(bf16x8, onesf), pb, l2[nt], 0, 0, 0);
#pragma unroll
        for (int mtd = 0; mtd < 4; mtd++)
          o[mtd][nt] = __builtin_amdgcn_mfma_f32_16x16x32_bf16(
              __builtin_bit_cast(bf16x8, vp[mtd]), pb, o[mtd][nt], 0, 0, 0);
      }
      __builtin_amdgcn_s_setprio(0);
    }
  }

  // l2[nt] rows are all identical = full denominator for q-column ln
  float inv[2];
#pragma unroll
  for (int nt = 0; nt < 2; nt++) inv[nt] = 1.0f / l2[nt][0];

#pragma unroll
  for (int nt = 0; nt < 2; nt++) {
    unsigned short* dst = X + (size_t)(b * SEQ + qw + nt * 16 + ln) * HIDDEN + h * HDIM;
#pragma unroll
    for (int mtd = 0; mtd < 4; mtd++) {
      s16x4 ov = pack4_bf16(o[mtd][nt][0] * inv[nt], o[mtd][nt][1] * inv[nt],
                            o[mtd][nt][2] * inv[nt], o[mtd][nt][3] * inv[nt]);
      *(s16x4*)(dst + mtd * 16 + quad * 4) = ov;
    }
  }
}

// ---------------------------------------------------------------------------
extern "C" void kernel_launch(void* const* d_in, const int* in_sizes, int n_in,
                              void* d_out, int out_size, void* d_ws, size_t ws_size,
                              hipStream_t stream) {
  const float* q_in = (const float*)d_in[0];
  const float* k_in = (const float*)d_in[1];
  const float* v_in = (const float*)d_in[2];
  const float* wq = (const float*)d_in[3];
  const float* bq = (const float*)d_in[4];
  const float* wk = (const float*)d_in[5];
  const float* bk = (const float*)d_in[6];
  const float* wv = (const float*)d_in[7];
  const float* bv = (const float*)d_in[8];
  const float* wf = (const float*)d_in[9];
  const float* bfb = (const float*)d_in[10];

  const size_t NX = (size_t)MTOT * HIDDEN;
  const size_t NW = (size_t)HIDDEN * HIDDEN;
  unsigned short* A = (unsigned short*)d_ws;
  unsigned short* Bx = A + NX;
  unsigned short* C = Bx + NX;
  unsigned short* W4 = C + NX;
  unsigned short* Qb = W4 + 4 * NW;
  unsigned short* Kb = Qb + NX;
  unsigned short* Vb = Kb + NX;

  cvt3<<<dim3(NX / 1024, 3), 256, 0, stream>>>(q_in, k_in, v_in, A, (int)NX);
  cvt4<<<dim3(NW / 1024, 4), 256, 0, stream>>>(wq, wk, wv, wf, W4, (int)NW);

  gemm_qkv<<<dim3(24, MTOT / 128), 256, 0, stream>>>(A, Bx, C, W4, bq, bk, bv, Qb, Kb, Vb);
  transpose_v<<<1024, 256, 0, stream>>>(Vb, Bx);
  attn6<<<dim3(NHEADS * 4, SEQ / 128), 256, 0, stream>>>(Qb, Kb, Bx, C);
  gemm_f<<<dim3(8, MTOT / 128), 256, 0, stream>>>(C, W4 + 3 * NW, bfb, (float*)d_out);
}

// Round 2
// 397.885 us; speedup vs baseline: 1.0840x; 1.0840x over previous
//
#include <hip/hip_runtime.h>
#include <stdint.h>

#define SEQ 2048
#define HIDDEN 1024
#define NHEADS 16
#define HDIM 64
#define MTOT 8192  // B*SEQ

// 1/sqrt(HDIM) * log2(e), folded into wq/bq so attn does exp2(S) directly
#define C1SCALE 0.1803368801111437f

typedef __bf16 bf16x8 __attribute__((ext_vector_type(8)));
typedef unsigned short u16x8 __attribute__((ext_vector_type(8)));
typedef short s16x4 __attribute__((ext_vector_type(4)));
typedef unsigned int u32x4 __attribute__((ext_vector_type(4)));
typedef float f32x4 __attribute__((ext_vector_type(4)));

#define GAS __attribute__((address_space(1)))
#define LAS __attribute__((address_space(3)))

__device__ __forceinline__ unsigned short bf16_rne(float f) {
  union { float f; unsigned int u; } v; v.f = f;
  return (unsigned short)((v.u + 0x7fffu + ((v.u >> 16) & 1u)) >> 16);
}

// pack 2 f32 -> 2 bf16 in one dword: round-half-up adds + one v_perm_b32
__device__ __forceinline__ unsigned int pk2(float lo, float hi) {
  unsigned int a = __builtin_bit_cast(unsigned int, hi) + 0x8000u;  // high short
  unsigned int b = __builtin_bit_cast(unsigned int, lo) + 0x8000u;  // low short
  return __builtin_amdgcn_perm(a, b, 0x07060302u);
}

__device__ __forceinline__ s16x4 pack4_bf16(float a, float b, float c, float d) {
  s16x4 r;
  r[0] = (short)bf16_rne(a); r[1] = (short)bf16_rne(b);
  r[2] = (short)bf16_rne(c); r[3] = (short)bf16_rne(d);
  return r;
}

__device__ __forceinline__ void gload_lds16(const unsigned short* g, unsigned short* l) {
  __builtin_amdgcn_global_load_lds((GAS void*)(unsigned short*)g, (LAS void*)l, 16, 0, 0);
}

// ---------------- fused fp32 -> bf16 conversions ---------------------------
__global__ __launch_bounds__(256) void cvt3(const float* __restrict__ a,
                                            const float* __restrict__ b,
                                            const float* __restrict__ c,
                                            unsigned short* __restrict__ out,
                                            int perSeg) {
  const int seg = blockIdx.y;
  const float* in = seg == 0 ? a : (seg == 1 ? b : c);
  int i = blockIdx.x * 256 + threadIdx.x;
  float4 v = ((const float4*)in)[i];
  ushort4 o;
  o.x = bf16_rne(v.x); o.y = bf16_rne(v.y);
  o.z = bf16_rne(v.z); o.w = bf16_rne(v.w);
  ((ushort4*)(out + (size_t)seg * perSeg))[i] = o;
}

// seg 0 (wq) is pre-scaled by C1SCALE (softmax scale folded into Q projection)
__global__ __launch_bounds__(256) void cvt4(const float* __restrict__ a,
                                            const float* __restrict__ b,
                                            const float* __restrict__ c,
                                            const float* __restrict__ d,
                                            unsigned short* __restrict__ out,
                                            int perSeg) {
  const int seg = blockIdx.y;
  const float* in = seg == 0 ? a : (seg == 1 ? b : (seg == 2 ? c : d));
  const float sc = (seg == 0) ? C1SCALE : 1.0f;
  int i = blockIdx.x * 256 + threadIdx.x;
  float4 v = ((const float4*)in)[i];
  ushort4 o;
  o.x = bf16_rne(v.x * sc); o.y = bf16_rne(v.y * sc);
  o.z = bf16_rne(v.z * sc); o.w = bf16_rne(v.w * sc);
  ((ushort4*)(out + (size_t)seg * perSeg))[i] = o;
}

// ---------------- fused QKV GEMM -------------------------------------------
__global__ __launch_bounds__(256) void gemm_qkv(const unsigned short* __restrict__ Xq,
                                                const unsigned short* __restrict__ Xk,
                                                const unsigned short* __restrict__ Xv,
                                                const unsigned short* __restrict__ W,
                                                const float* __restrict__ bq,
                                                const float* __restrict__ bk,
                                                const float* __restrict__ bv,
                                                unsigned short* __restrict__ Qb,
                                                unsigned short* __restrict__ Kb,
                                                unsigned short* __restrict__ Vb) {
  __shared__ unsigned short As[128 * 32];
  __shared__ unsigned short Bs[128 * 32];
  const int tid = threadIdx.x;
  const int lane = tid & 63, w = tid >> 6;
  const int quad = lane >> 4, ln = lane & 15;
  const int wm = w & 1, wn = w >> 1;
  const int mBase = blockIdx.y * 128, nBase = blockIdx.x * 128;
  const int seg = blockIdx.x >> 3;
  const unsigned short* A = seg == 0 ? Xq : (seg == 1 ? Xk : Xv);
  const float* bias = seg == 0 ? bq : (seg == 1 ? bk : bv);
  const float bscale = seg == 0 ? C1SCALE : 1.0f;
  unsigned short* outp = seg == 0 ? Qb : (seg == 1 ? Kb : Vb);
  const int K = HIDDEN;

  f32x4 acc[4][4];
  f32x4 zero = {0.f, 0.f, 0.f, 0.f};
#pragma unroll
  for (int i = 0; i < 4; i++)
#pragma unroll
    for (int j = 0; j < 4; j++) acc[i][j] = zero;

  const int e0 = tid * 8;
  const int e1 = (256 + tid) * 8;
  const int r0 = e0 >> 5, c0 = e0 & 31;
  const int r1 = e1 >> 5, c1 = e1 & 31;
  const unsigned short* Ap0 = A + (size_t)(mBase + r0) * K + c0;
  const unsigned short* Ap1 = A + (size_t)(mBase + r1) * K + c1;
  const unsigned short* Wp0 = W + (size_t)(nBase + r0) * K + c0;
  const unsigned short* Wp1 = W + (size_t)(nBase + r1) * K + c1;

  for (int k0 = 0; k0 < K; k0 += 32) {
    gload_lds16(Ap0 + k0, &As[e0]);
    gload_lds16(Ap1 + k0, &As[e1]);
    gload_lds16(Wp0 + k0, &Bs[e0]);
    gload_lds16(Wp1 + k0, &Bs[e1]);
    __syncthreads();
    u16x8 af[4], bfr[4];
#pragma unroll
    for (int mi = 0; mi < 4; mi++)
      af[mi] = *(const u16x8*)&As[(wm * 64 + mi * 16 + ln) * 32 + quad * 8];
#pragma unroll
    for (int ni = 0; ni < 4; ni++)
      bfr[ni] = *(const u16x8*)&Bs[(wn * 64 + ni * 16 + ln) * 32 + quad * 8];
#pragma unroll
    for (int mi = 0; mi < 4; mi++)
#pragma unroll
      for (int ni = 0; ni < 4; ni++)
        acc[mi][ni] = __builtin_amdgcn_mfma_f32_16x16x32_bf16(
            __builtin_bit_cast(bf16x8, af[mi]), __builtin_bit_cast(bf16x8, bfr[ni]),
            acc[mi][ni], 0, 0, 0);
    __syncthreads();
  }

#pragma unroll
  for (int ni = 0; ni < 4; ni++) {
    const int colg = nBase + wn * 64 + ni * 16 + ln;
    const int col = colg & 1023;
    const float bvv = bias[col] * bscale;
#pragma unroll
    for (int mi = 0; mi < 4; mi++) {
      const int row = mBase + wm * 64 + mi * 16 + quad * 4;
#pragma unroll
      for (int r = 0; r < 4; r++)
        outp[(size_t)(row + r) * HIDDEN + col] = bf16_rne(acc[mi][ni][r] + bvv);
    }
  }
}

// ---------------- final GEMM (fp32 out) ------------------------------------
__global__ __launch_bounds__(256) void gemm_f(const unsigned short* __restrict__ A,
                                              const unsigned short* __restrict__ W,
                                              const float* __restrict__ bias,
                                              float* __restrict__ Cv) {
  __shared__ unsigned short As[128 * 32];
  __shared__ unsigned short Bs[128 * 32];
  const int tid = threadIdx.x;
  const int lane = tid & 63, w = tid >> 6;
  const int quad = lane >> 4, ln = lane & 15;
  const int wm = w & 1, wn = w >> 1;
  const int mBase = blockIdx.y * 128, nBase = blockIdx.x * 128;
  const int K = HIDDEN, N = HIDDEN;

  f32x4 acc[4][4];
  f32x4 zero = {0.f, 0.f, 0.f, 0.f};
#pragma unroll
  for (int i = 0; i < 4; i++)
#pragma unroll
    for (int j = 0; j < 4; j++) acc[i][j] = zero;

  const int e0 = tid * 8;
  const int e1 = (256 + tid) * 8;
  const int r0 = e0 >> 5, c0 = e0 & 31;
  const int r1 = e1 >> 5, c1 = e1 & 31;
  const unsigned short* Ap0 = A + (size_t)(mBase + r0) * K + c0;
  const unsigned short* Ap1 = A + (size_t)(mBase + r1) * K + c1;
  const unsigned short* Wp0 = W + (size_t)(nBase + r0) * K + c0;
  const unsigned short* Wp1 = W + (size_t)(nBase + r1) * K + c1;

  for (int k0 = 0; k0 < K; k0 += 32) {
    gload_lds16(Ap0 + k0, &As[e0]);
    gload_lds16(Ap1 + k0, &As[e1]);
    gload_lds16(Wp0 + k0, &Bs[e0]);
    gload_lds16(Wp1 + k0, &Bs[e1]);
    __syncthreads();
    u16x8 af[4], bfr[4];
#pragma unroll
    for (int mi = 0; mi < 4; mi++)
      af[mi] = *(const u16x8*)&As[(wm * 64 + mi * 16 + ln) * 32 + quad * 8];
#pragma unroll
    for (int ni = 0; ni < 4; ni++)
      bfr[ni] = *(const u16x8*)&Bs[(wn * 64 + ni * 16 + ln) * 32 + quad * 8];
#pragma unroll
    for (int mi = 0; mi < 4; mi++)
#pragma unroll
      for (int ni = 0; ni < 4; ni++)
        acc[mi][ni] = __builtin_amdgcn_mfma_f32_16x16x32_bf16(
            __builtin_bit_cast(bf16x8, af[mi]), __builtin_bit_cast(bf16x8, bfr[ni]),
            acc[mi][ni], 0, 0, 0);
    __syncthreads();
  }

#pragma unroll
  for (int ni = 0; ni < 4; ni++) {
    const int col = nBase + wn * 64 + ni * 16 + ln;
    const float bvv = bias[col];
#pragma unroll
    for (int mi = 0; mi < 4; mi++) {
      const int row = mBase + wm * 64 + mi * 16 + quad * 4;
#pragma unroll
      for (int r = 0; r < 4; r++)
        Cv[(size_t)(row + r) * N + col] = acc[mi][ni][r] + bvv;
    }
  }
}

// ---------------- V transpose: fragment-linear A-frags for register PV -----
// Output layout per tile t = bh*16+kt (8192 elems):
//   frag f = g*4+mtd (g: 32-key group, mtd: 16-d block), 512 elems each.
//   Within frag: lane (quad,ln) holds u16x8 at f*512 + lane*8, element j =
//   V[key = g*32 + (j>>2)*16 + quad*4 + (j&3)][d = mtd*16 + ln]
//   (key permutation matches P's B-fragment layout from the swapped QK^T).
// Each wave-load in attn is 1024 contiguous bytes -> perfectly coalesced.
__global__ __launch_bounds__(256) void transpose_v(const unsigned short* __restrict__ Vb,
                                                   unsigned short* __restrict__ Vt) {
  __shared__ unsigned short L[128 * 90];
  const int t = blockIdx.x;  // 1024 tiles
  const int bh = t >> 4, kt = t & 15;
  const int b = bh >> 4, h = bh & 15;
  const int tid = threadIdx.x;
  {
    const int key = tid >> 1, hf = tid & 1;
    const unsigned short* src =
        Vb + ((size_t)(b * SEQ + kt * 128 + key)) * HIDDEN + h * HDIM + hf * 32;
    u16x8 a0 = *(const u16x8*)(src);
    u16x8 a1 = *(const u16x8*)(src + 8);
    u16x8 a2 = *(const u16x8*)(src + 16);
    u16x8 a3 = *(const u16x8*)(src + 24);
    unsigned short* dst = &L[key * 90 + hf * 32];
    *(u16x8*)(dst) = a0;
    *(u16x8*)(dst + 8) = a1;
    *(u16x8*)(dst + 16) = a2;
    *(u16x8*)(dst + 24) = a3;
  }
  __syncthreads();
  const int lane = tid & 63, w = tid >> 6;
  const int quad = lane >> 4, ln = lane & 15;
  unsigned short* out = Vt + (size_t)t * 8192;
#pragma unroll
  for (int gg = 0; gg < 4; gg++) {
    const int f = w * 4 + gg;
    const int g = f >> 2, mtd = f & 3;
    u16x8 v;
#pragma unroll
    for (int j = 0; j < 8; j++) {
      const int key = g * 32 + (j >> 2) * 16 + quad * 4 + (j & 3);
      v[j] = L[key * 90 + mtd * 16 + ln];
    }
    *(u16x8*)(out + f * 512 + lane * 8) = v;
  }
}

// ---------------- flash attention v7: LDS-staged K, register V -------------
// Round-1 lesson: per-wave global K loads (depth-2/4 ring) expose ~300cy L2
// latency 16x per kt -> ~6.7k cy/kt/wave, dur pinned at 179us regardless of
// barrier structure. Fix: K tile (128x64, 16KB) staged via global_load_lds
// DMA, double-buffered, 1 barrier/kt -> prefetch distance = full kt.
// LDS K reads are XOR-swizzled (chunk ^= row&7, G4 attn fix): swizzle applied
// on the DMA's *global* source (rule #21), read back with same XOR -> <=2-way
// bank aliasing (free). V stays register-fragment (fragment-linear Vt),
// double-buffered vA/vB, group g+1 issued at g's top (~1 full phase ahead).
// vmcnt is FIFO: the kt+1 DMA is issued at g=3's top, AFTER all V issues of
// the tile, so no V wait implies a DMA drain; only the barrier (which must
// wait for the DMA anyway) drains it.
__global__ __launch_bounds__(256, 4) void attn7(const unsigned short* __restrict__ Q,
                                                const unsigned short* __restrict__ K,
                                                const unsigned short* __restrict__ Vt,
                                                unsigned short* __restrict__ X) {
  __shared__ unsigned short Ks[2][128 * 64];  // 2 x 16 KB, XOR-swizzled content
  const int tid = threadIdx.x, lane = tid & 63, w = tid >> 6;
  const int quad = lane >> 4, ln = lane & 15;
  const int bh = blockIdx.x, b = bh >> 4, h = bh & 15;
  const size_t base = (size_t)b * SEQ * HIDDEN + (size_t)h * HDIM;
  const unsigned short* Qh = Q + base;
  const unsigned short* Kh = K + base;
  const unsigned short* vtile = Vt + (size_t)bh * 16 * 8192;
  const int qw = blockIdx.y * 128 + w * 32;

  // K DMA: thread covers 16B chunks {tid + s*256}, s=0..3. chunk c: row=c>>3,
  // cb=c&7. LDS dest = linear c*16B (lane-linear per wave, as HW requires);
  // global source chunk = cb ^ (row&7)  (row&7 invariant across shots).
  const int kr0 = tid >> 3, kcb = tid & 7;
  const unsigned short* ksrc = Kh + (size_t)kr0 * HIDDEN + ((kcb ^ (kr0 & 7)) * 8);

  // swizzled K fragment read offsets (elems): row = mt*16+ln, chunk kk*4+quad
  const int krd0 = ln * 64 + ((quad ^ (ln & 7)) * 8);        // kk=0
  const int krd1 = ln * 64 + (((4 | quad) ^ (ln & 7)) * 8);  // kk=1

  // resident Q B-frags: B[k=d=kk2*32+quad*8+j][n=q=nt*16+ln]
  u16x8 qf[2][2];
#pragma unroll
  for (int nt = 0; nt < 2; nt++)
#pragma unroll
    for (int kk2 = 0; kk2 < 2; kk2++)
      qf[nt][kk2] = *(const u16x8*)(Qh + (size_t)(qw + nt * 16 + ln) * HIDDEN + kk2 * 32 + quad * 8);

  f32x4 o[4][2];
  f32x4 zero = {0.f, 0.f, 0.f, 0.f};
#pragma unroll
  for (int mtd = 0; mtd < 4; mtd++)
#pragma unroll
    for (int nt = 0; nt < 2; nt++) o[mtd][nt] = zero;
  f32x4 l2[2] = {zero, zero};

  u16x8 onesf;
#pragma unroll
  for (int j = 0; j < 8; j++) onesf[j] = 0x3F80;  // bf16 1.0

  u16x8 vA[4], vB[4];

  // prologue: stage K(0) into buf0; prefetch V(kt=0, g=0) into vA
  {
    unsigned short* kd = &Ks[0][tid * 8];
    gload_lds16(ksrc, kd);
    gload_lds16(ksrc + 32 * HIDDEN, kd + 2048);
    gload_lds16(ksrc + 64 * HIDDEN, kd + 4096);
    gload_lds16(ksrc + 96 * HIDDEN, kd + 6144);
  }
#pragma unroll
  for (int mtd = 0; mtd < 4; mtd++)
    vA[mtd] = *(const u16x8*)(vtile + mtd * 512 + lane * 8);

  for (int kt = 0; kt < 16; ++kt) {
    __syncthreads();  // drains own DMA (vmcnt0) -> K(kt) visible; buf swap safe
    const unsigned short* kb = &Ks[kt & 1][0];
    const unsigned short* vt = vtile + kt * 8192;
#pragma unroll
    for (int g = 0; g < 4; g++) {
      // V prefetch: g<3 -> group g+1 of this tile; g==3 -> group 0 of kt+1
      if (g < 3) {
#pragma unroll
        for (int mtd = 0; mtd < 4; mtd++) {
          u16x8 v_ = *(const u16x8*)(vt + ((g + 1) * 4 + mtd) * 512 + lane * 8);
          if (g & 1) vA[mtd] = v_; else vB[mtd] = v_;
        }
      } else if (kt < 15) {
#pragma unroll
        for (int mtd = 0; mtd < 4; mtd++)
          vA[mtd] = *(const u16x8*)(vt + 8192 + mtd * 512 + lane * 8);
        // K DMA for kt+1: issued after ALL V loads of this tile (vmcnt FIFO)
        const unsigned short* ks = ksrc + (size_t)(kt + 1) * (128 * HIDDEN);
        unsigned short* kd = &Ks[(kt + 1) & 1][tid * 8];
        gload_lds16(ks, kd);
        gload_lds16(ks + 32 * HIDDEN, kd + 2048);
        gload_lds16(ks + 64 * HIDDEN, kd + 4096);
        gload_lds16(ks + 96 * HIDDEN, kd + 6144);
      }
      u32x4 P[2];
#pragma unroll
      for (int half = 0; half < 2; half++) {
        const int mt = 2 * g + half;
        const u16x8 kf0 = *(const u16x8*)&kb[mt * 1024 + krd0];
        const u16x8 kf1 = *(const u16x8*)&kb[mt * 1024 + krd1];
        f32x4 s0 = zero, s1 = zero;
        __builtin_amdgcn_s_setprio(1);
        s0 = __builtin_amdgcn_mfma_f32_16x16x32_bf16(
            __builtin_bit_cast(bf16x8, kf0), __builtin_bit_cast(bf16x8, qf[0][0]), s0, 0, 0, 0);
        s0 = __builtin_amdgcn_mfma_f32_16x16x32_bf16(
            __builtin_bit_cast(bf16x8, kf1), __builtin_bit_cast(bf16x8, qf[0][1]), s0, 0, 0, 0);
        s1 = __builtin_amdgcn_mfma_f32_16x16x32_bf16(
            __builtin_bit_cast(bf16x8, kf0), __builtin_bit_cast(bf16x8, qf[1][0]), s1, 0, 0, 0);
        s1 = __builtin_amdgcn_mfma_f32_16x16x32_bf16(
            __builtin_bit_cast(bf16x8, kf1), __builtin_bit_cast(bf16x8, qf[1][1]), s1, 0, 0, 0);
        __builtin_amdgcn_s_setprio(0);
        float e0[4], e1[4];
#pragma unroll
        for (int r = 0; r < 4; r++) {
          e0[r] = __builtin_exp2f(s0[r]);
          e1[r] = __builtin_exp2f(s1[r]);
        }
        if (half == 0) {
          P[0][0] = pk2(e0[0], e0[1]); P[0][1] = pk2(e0[2], e0[3]);
          P[1][0] = pk2(e1[0], e1[1]); P[1][1] = pk2(e1[2], e1[3]);
        } else {
          P[0][2] = pk2(e0[0], e0[1]); P[0][3] = pk2(e0[2], e0[3]);
          P[1][2] = pk2(e1[0], e1[1]); P[1][3] = pk2(e1[2], e1[3]);
        }
      }
      // PV + denominator for this 32-key group (cur = g even ? vA : vB)
      __builtin_amdgcn_s_setprio(1);
#pragma unroll
      for (int nt = 0; nt < 2; nt++) {
        bf16x8 pb = __builtin_bit_cast(bf16x8, P[nt]);
        l2[nt] = __builtin_amdgcn_mfma_f32_16x16x32_bf16(
            __builtin_bit_cast(bf16x8, onesf), pb, l2[nt], 0, 0, 0);
#pragma unroll
        for (int mtd = 0; mtd < 4; mtd++) {
          u16x8 vv = (g & 1) ? vB[mtd] : vA[mtd];
          o[mtd][nt] = __builtin_amdgcn_mfma_f32_16x16x32_bf16(
              __builtin_bit_cast(bf16x8, vv), pb, o[mtd][nt], 0, 0, 0);
        }
      }
      __builtin_amdgcn_s_setprio(0);
    }
  }

  // l2[nt] rows are all identical = full denominator for q-column ln
  float inv[2];
#pragma unroll
  for (int nt = 0; nt < 2; nt++) inv[nt] = 1.0f / l2[nt][0];

#pragma unroll
  for (int nt = 0; nt < 2; nt++) {
    unsigned short* dst = X + (size_t)(b * SEQ + qw + nt * 16 + ln) * HIDDEN + h * HDIM;
#pragma unroll
    for (int mtd = 0; mtd < 4; mtd++) {
      s16x4 ov = pack4_bf16(o[mtd][nt][0] * inv[nt], o[mtd][nt][1] * inv[nt],
                            o[mtd][nt][2] * inv[nt], o[mtd][nt][3] * inv[nt]);
      *(s16x4*)(dst + mtd * 16 + quad * 4) = ov;
    }
  }
}

// ---------------------------------------------------------------------------
extern "C" void kernel_launch(void* const* d_in, const int* in_sizes, int n_in,
                              void* d_out, int out_size, void* d_ws, size_t ws_size,
                              hipStream_t stream) {
  const float* q_in = (const float*)d_in[0];
  const float* k_in = (const float*)d_in[1];
  const float* v_in = (const float*)d_in[2];
  const float* wq = (const float*)d_in[3];
  const float* bq = (const float*)d_in[4];
  const float* wk = (const float*)d_in[5];
  const float* bk = (const float*)d_in[6];
  const float* wv = (const float*)d_in[7];
  const float* bv = (const float*)d_in[8];
  const float* wf = (const float*)d_in[9];
  const float* bfb = (const float*)d_in[10];

  const size_t NX = (size_t)MTOT * HIDDEN;
  const size_t NW = (size_t)HIDDEN * HIDDEN;
  unsigned short* A = (unsigned short*)d_ws;
  unsigned short* Bx = A + NX;
  unsigned short* C = Bx + NX;
  unsigned short* W4 = C + NX;
  unsigned short* Qb = W4 + 4 * NW;
  unsigned short* Kb = Qb + NX;
  unsigned short* Vb = Kb + NX;

  cvt3<<<dim3(NX / 1024, 3), 256, 0, stream>>>(q_in, k_in, v_in, A, (int)NX);
  cvt4<<<dim3(NW / 1024, 4), 256, 0, stream>>>(wq, wk, wv, wf, W4, (int)NW);

  gemm_qkv<<<dim3(24, MTOT / 128), 256, 0, stream>>>(A, Bx, C, W4, bq, bk, bv, Qb, Kb, Vb);
  transpose_v<<<1024, 256, 0, stream>>>(Vb, Bx);
  attn7<<<dim3(NHEADS * 4, SEQ / 128), 256, 0, stream>>>(Qb, Kb, Bx, C);
  gemm_f<<<dim3(8, MTOT / 128), 256, 0, stream>>>(C, W4 + 3 * NW, bfb, (float*)d_out);
}

// Round 3
// 369.791 us; speedup vs baseline: 1.1664x; 1.0760x over previous
//
#include <hip/hip_runtime.h>
#include <stdint.h>

#define SEQ 2048
#define HIDDEN 1024
#define NHEADS 16
#define HDIM 64
#define MTOT 8192  // B*SEQ

// 1/sqrt(HDIM) * log2(e), folded into wq/bq so attn does exp2(S) directly
#define C1SCALE 0.1803368801111437f

typedef __bf16 bf16x8 __attribute__((ext_vector_type(8)));
typedef unsigned short u16x8 __attribute__((ext_vector_type(8)));
typedef short s16x4 __attribute__((ext_vector_type(4)));
typedef unsigned int u32x4 __attribute__((ext_vector_type(4)));
typedef float f32x4 __attribute__((ext_vector_type(4)));

#define GAS __attribute__((address_space(1)))
#define LAS __attribute__((address_space(3)))

__device__ __forceinline__ unsigned short bf16_rne(float f) {
  union { float f; unsigned int u; } v; v.f = f;
  return (unsigned short)((v.u + 0x7fffu + ((v.u >> 16) & 1u)) >> 16);
}

// pack 2 f32 -> 2 bf16 in one dword: round-half-up adds + one v_perm_b32
__device__ __forceinline__ unsigned int pk2(float lo, float hi) {
  unsigned int a = __builtin_bit_cast(unsigned int, hi) + 0x8000u;  // high short
  unsigned int b = __builtin_bit_cast(unsigned int, lo) + 0x8000u;  // low short
  return __builtin_amdgcn_perm(a, b, 0x07060302u);
}

__device__ __forceinline__ s16x4 pack4_bf16(float a, float b, float c, float d) {
  s16x4 r;
  r[0] = (short)bf16_rne(a); r[1] = (short)bf16_rne(b);
  r[2] = (short)bf16_rne(c); r[3] = (short)bf16_rne(d);
  return r;
}

__device__ __forceinline__ void gload_lds16(const unsigned short* g, unsigned short* l) {
  __builtin_amdgcn_global_load_lds((GAS void*)(unsigned short*)g, (LAS void*)l, 16, 0, 0);
}

// ---------------- fused fp32 -> bf16 conversions ---------------------------
__global__ __launch_bounds__(256) void cvt3(const float* __restrict__ a,
                                            const float* __restrict__ b,
                                            const float* __restrict__ c,
                                            unsigned short* __restrict__ out,
                                            int perSeg) {
  const int seg = blockIdx.y;
  const float* in = seg == 0 ? a : (seg == 1 ? b : c);
  int i = blockIdx.x * 256 + threadIdx.x;
  float4 v = ((const float4*)in)[i];
  ushort4 o;
  o.x = bf16_rne(v.x); o.y = bf16_rne(v.y);
  o.z = bf16_rne(v.z); o.w = bf16_rne(v.w);
  ((ushort4*)(out + (size_t)seg * perSeg))[i] = o;
}

// seg 0 (wq) is pre-scaled by C1SCALE (softmax scale folded into Q projection)
__global__ __launch_bounds__(256) void cvt4(const float* __restrict__ a,
                                            const float* __restrict__ b,
                                            const float* __restrict__ c,
                                            const float* __restrict__ d,
                                            unsigned short* __restrict__ out,
                                            int perSeg) {
  const int seg = blockIdx.y;
  const float* in = seg == 0 ? a : (seg == 1 ? b : (seg == 2 ? c : d));
  const float sc = (seg == 0) ? C1SCALE : 1.0f;
  int i = blockIdx.x * 256 + threadIdx.x;
  float4 v = ((const float4*)in)[i];
  ushort4 o;
  o.x = bf16_rne(v.x * sc); o.y = bf16_rne(v.y * sc);
  o.z = bf16_rne(v.z * sc); o.w = bf16_rne(v.w * sc);
  ((ushort4*)(out + (size_t)seg * perSeg))[i] = o;
}

// ---------------- fused QKV GEMM -------------------------------------------
__global__ __launch_bounds__(256) void gemm_qkv(const unsigned short* __restrict__ Xq,
                                                const unsigned short* __restrict__ Xk,
                                                const unsigned short* __restrict__ Xv,
                                                const unsigned short* __restrict__ W,
                                                const float* __restrict__ bq,
                                                const float* __restrict__ bk,
                                                const float* __restrict__ bv,
                                                unsigned short* __restrict__ Qb,
                                                unsigned short* __restrict__ Kb,
                                                unsigned short* __restrict__ Vb) {
  __shared__ unsigned short As[128 * 32];
  __shared__ unsigned short Bs[128 * 32];
  const int tid = threadIdx.x;
  const int lane = tid & 63, w = tid >> 6;
  const int quad = lane >> 4, ln = lane & 15;
  const int wm = w & 1, wn = w >> 1;
  const int mBase = blockIdx.y * 128, nBase = blockIdx.x * 128;
  const int seg = blockIdx.x >> 3;
  const unsigned short* A = seg == 0 ? Xq : (seg == 1 ? Xk : Xv);
  const float* bias = seg == 0 ? bq : (seg == 1 ? bk : bv);
  const float bscale = seg == 0 ? C1SCALE : 1.0f;
  unsigned short* outp = seg == 0 ? Qb : (seg == 1 ? Kb : Vb);
  const int K = HIDDEN;

  f32x4 acc[4][4];
  f32x4 zero = {0.f, 0.f, 0.f, 0.f};
#pragma unroll
  for (int i = 0; i < 4; i++)
#pragma unroll
    for (int j = 0; j < 4; j++) acc[i][j] = zero;

  const int e0 = tid * 8;
  const int e1 = (256 + tid) * 8;
  const int r0 = e0 >> 5, c0 = e0 & 31;
  const int r1 = e1 >> 5, c1 = e1 & 31;
  const unsigned short* Ap0 = A + (size_t)(mBase + r0) * K + c0;
  const unsigned short* Ap1 = A + (size_t)(mBase + r1) * K + c1;
  const unsigned short* Wp0 = W + (size_t)(nBase + r0) * K + c0;
  const unsigned short* Wp1 = W + (size_t)(nBase + r1) * K + c1;

  for (int k0 = 0; k0 < K; k0 += 32) {
    gload_lds16(Ap0 + k0, &As[e0]);
    gload_lds16(Ap1 + k0, &As[e1]);
    gload_lds16(Wp0 + k0, &Bs[e0]);
    gload_lds16(Wp1 + k0, &Bs[e1]);
    __syncthreads();
    u16x8 af[4], bfr[4];
#pragma unroll
    for (int mi = 0; mi < 4; mi++)
      af[mi] = *(const u16x8*)&As[(wm * 64 + mi * 16 + ln) * 32 + quad * 8];
#pragma unroll
    for (int ni = 0; ni < 4; ni++)
      bfr[ni] = *(const u16x8*)&Bs[(wn * 64 + ni * 16 + ln) * 32 + quad * 8];
#pragma unroll
    for (int mi = 0; mi < 4; mi++)
#pragma unroll
      for (int ni = 0; ni < 4; ni++)
        acc[mi][ni] = __builtin_amdgcn_mfma_f32_16x16x32_bf16(
            __builtin_bit_cast(bf16x8, af[mi]), __builtin_bit_cast(bf16x8, bfr[ni]),
            acc[mi][ni], 0, 0, 0);
    __syncthreads();
  }

#pragma unroll
  for (int ni = 0; ni < 4; ni++) {
    const int colg = nBase + wn * 64 + ni * 16 + ln;
    const int col = colg & 1023;
    const float bvv = bias[col] * bscale;
#pragma unroll
    for (int mi = 0; mi < 4; mi++) {
      const int row = mBase + wm * 64 + mi * 16 + quad * 4;
#pragma unroll
      for (int r = 0; r < 4; r++)
        outp[(size_t)(row + r) * HIDDEN + col] = bf16_rne(acc[mi][ni][r] + bvv);
    }
  }
}

// ---------------- final GEMM (fp32 out) ------------------------------------
__global__ __launch_bounds__(256) void gemm_f(const unsigned short* __restrict__ A,
                                              const unsigned short* __restrict__ W,
                                              const float* __restrict__ bias,
                                              float* __restrict__ Cv) {
  __shared__ unsigned short As[128 * 32];
  __shared__ unsigned short Bs[128 * 32];
  const int tid = threadIdx.x;
  const int lane = tid & 63, w = tid >> 6;
  const int quad = lane >> 4, ln = lane & 15;
  const int wm = w & 1, wn = w >> 1;
  const int mBase = blockIdx.y * 128, nBase = blockIdx.x * 128;
  const int K = HIDDEN, N = HIDDEN;

  f32x4 acc[4][4];
  f32x4 zero = {0.f, 0.f, 0.f, 0.f};
#pragma unroll
  for (int i = 0; i < 4; i++)
#pragma unroll
    for (int j = 0; j < 4; j++) acc[i][j] = zero;

  const int e0 = tid * 8;
  const int e1 = (256 + tid) * 8;
  const int r0 = e0 >> 5, c0 = e0 & 31;
  const int r1 = e1 >> 5, c1 = e1 & 31;
  const unsigned short* Ap0 = A + (size_t)(mBase + r0) * K + c0;
  const unsigned short* Ap1 = A + (size_t)(mBase + r1) * K + c1;
  const unsigned short* Wp0 = W + (size_t)(nBase + r0) * K + c0;
  const unsigned short* Wp1 = W + (size_t)(nBase + r1) * K + c1;

  for (int k0 = 0; k0 < K; k0 += 32) {
    gload_lds16(Ap0 + k0, &As[e0]);
    gload_lds16(Ap1 + k0, &As[e1]);
    gload_lds16(Wp0 + k0, &Bs[e0]);
    gload_lds16(Wp1 + k0, &Bs[e1]);
    __syncthreads();
    u16x8 af[4], bfr[4];
#pragma unroll
    for (int mi = 0; mi < 4; mi++)
      af[mi] = *(const u16x8*)&As[(wm * 64 + mi * 16 + ln) * 32 + quad * 8];
#pragma unroll
    for (int ni = 0; ni < 4; ni++)
      bfr[ni] = *(const u16x8*)&Bs[(wn * 64 + ni * 16 + ln) * 32 + quad * 8];
#pragma unroll
    for (int mi = 0; mi < 4; mi++)
#pragma unroll
      for (int ni = 0; ni < 4; ni++)
        acc[mi][ni] = __builtin_amdgcn_mfma_f32_16x16x32_bf16(
            __builtin_bit_cast(bf16x8, af[mi]), __builtin_bit_cast(bf16x8, bfr[ni]),
            acc[mi][ni], 0, 0, 0);
    __syncthreads();
  }

#pragma unroll
  for (int ni = 0; ni < 4; ni++) {
    const int col = nBase + wn * 64 + ni * 16 + ln;
    const float bvv = bias[col];
#pragma unroll
    for (int mi = 0; mi < 4; mi++) {
      const int row = mBase + wm * 64 + mi * 16 + quad * 4;
#pragma unroll
      for (int r = 0; r < 4; r++)
        Cv[(size_t)(row + r) * N + col] = acc[mi][ni][r] + bvv;
    }
  }
}

// ---------------- V transpose: fragment-linear A-frags for register PV -----
// Output layout per tile t = bh*16+kt (8192 elems):
//   frag f = g*4+mtd (g: 32-key group, mtd: 16-d block), 512 elems each.
//   Within frag: lane (quad,ln) holds u16x8 at f*512 + lane*8, element j =
//   V[key = g*32 + (j>>2)*16 + quad*4 + (j&3)][d = mtd*16 + ln]
//   (key permutation matches P's B-fragment layout from the swapped QK^T).
// Each wave-load in attn is 1024 contiguous bytes -> perfectly coalesced.
__global__ __launch_bounds__(256) void transpose_v(const unsigned short* __restrict__ Vb,
                                                   unsigned short* __restrict__ Vt) {
  __shared__ unsigned short L[128 * 90];
  const int t = blockIdx.x;  // 1024 tiles
  const int bh = t >> 4, kt = t & 15;
  const int b = bh >> 4, h = bh & 15;
  const int tid = threadIdx.x;
  {
    const int key = tid >> 1, hf = tid & 1;
    const unsigned short* src =
        Vb + ((size_t)(b * SEQ + kt * 128 + key)) * HIDDEN + h * HDIM + hf * 32;
    u16x8 a0 = *(const u16x8*)(src);
    u16x8 a1 = *(const u16x8*)(src + 8);
    u16x8 a2 = *(const u16x8*)(src + 16);
    u16x8 a3 = *(const u16x8*)(src + 24);
    unsigned short* dst = &L[key * 90 + hf * 32];
    *(u16x8*)(dst) = a0;
    *(u16x8*)(dst + 8) = a1;
    *(u16x8*)(dst + 16) = a2;
    *(u16x8*)(dst + 24) = a3;
  }
  __syncthreads();
  const int lane = tid & 63, w = tid >> 6;
  const int quad = lane >> 4, ln = lane & 15;
  unsigned short* out = Vt + (size_t)t * 8192;
#pragma unroll
  for (int gg = 0; gg < 4; gg++) {
    const int f = w * 4 + gg;
    const int g = f >> 2, mtd = f & 3;
    u16x8 v;
#pragma unroll
    for (int j = 0; j < 8; j++) {
      const int key = g * 32 + (j >> 2) * 16 + quad * 4 + (j & 3);
      v[j] = L[key * 90 + mtd * 16 + ln];
    }
    *(u16x8*)(out + f * 512 + lane * 8) = v;
  }
}

// ---------------- flash attention v8: LDS-staged K, single-buffer reg V ----
// v7 post-mortem: WRITE_SIZE 69MB (vs 16.4 ideal) = scratch spill under the
// (256,4) 128-VGPR cap; vA/vB V double-buffer (+32 VGPR) was the marginal
// consumer. v8: single vp[4] loaded at each group's top -> issue-to-use
// distance = QK+exp2 phase (~450cy) covers L2 (~200cy). Live state ~78 arch
// VGPR + 40 acc = ~118 <= 128 -> no spill, 4 blocks/CU resident.
// K path unchanged from v7: 16KB tile DMA'd via global_load_lds, double
// buffered, XOR-swizzled on the global source (rule #21), 1 barrier/kt.
// vmcnt FIFO: kt+1 DMA issued at g=3 AFTER that group's V loads, so PV's
// vp-wait never drains the DMA; only the barrier does (a full phase later).
__global__ __launch_bounds__(256, 4) void attn8(const unsigned short* __restrict__ Q,
                                                const unsigned short* __restrict__ K,
                                                const unsigned short* __restrict__ Vt,
                                                unsigned short* __restrict__ X) {
  __shared__ unsigned short Ks[2][128 * 64];  // 2 x 16 KB, XOR-swizzled content
  const int tid = threadIdx.x, lane = tid & 63, w = tid >> 6;
  const int quad = lane >> 4, ln = lane & 15;
  const int bh = blockIdx.x, b = bh >> 4, h = bh & 15;
  const size_t base = (size_t)b * SEQ * HIDDEN + (size_t)h * HDIM;
  const unsigned short* Qh = Q + base;
  const unsigned short* Kh = K + base;
  const unsigned short* vtile = Vt + (size_t)bh * 16 * 8192;
  const int qw = blockIdx.y * 128 + w * 32;

  // K DMA: thread covers 16B chunks {tid + s*256}, s=0..3. chunk c: row=c>>3,
  // cb=c&7. LDS dest = linear c*16B (lane-linear per wave, as HW requires);
  // global source chunk = cb ^ (row&7)  (row&7 invariant across shots).
  const int kr0 = tid >> 3, kcb = tid & 7;
  const unsigned short* ksrc = Kh + (size_t)kr0 * HIDDEN + ((kcb ^ (kr0 & 7)) * 8);

  // swizzled K fragment read offsets (elems): row = mt*16+ln, chunk kk*4+quad
  const int krd0 = ln * 64 + ((quad ^ (ln & 7)) * 8);        // kk=0
  const int krd1 = ln * 64 + (((4 | quad) ^ (ln & 7)) * 8);  // kk=1

  // resident Q B-frags: B[k=d=kk2*32+quad*8+j][n=q=nt*16+ln]
  u16x8 qf[2][2];
#pragma unroll
  for (int nt = 0; nt < 2; nt++)
#pragma unroll
    for (int kk2 = 0; kk2 < 2; kk2++)
      qf[nt][kk2] = *(const u16x8*)(Qh + (size_t)(qw + nt * 16 + ln) * HIDDEN + kk2 * 32 + quad * 8);

  f32x4 o[4][2];
  f32x4 zero = {0.f, 0.f, 0.f, 0.f};
#pragma unroll
  for (int mtd = 0; mtd < 4; mtd++)
#pragma unroll
    for (int nt = 0; nt < 2; nt++) o[mtd][nt] = zero;
  f32x4 l2[2] = {zero, zero};

  u16x8 onesf;
#pragma unroll
  for (int j = 0; j < 8; j++) onesf[j] = 0x3F80;  // bf16 1.0

  // prologue: stage K(0) into buf0
  {
    unsigned short* kd = &Ks[0][tid * 8];
    gload_lds16(ksrc, kd);
    gload_lds16(ksrc + 32 * HIDDEN, kd + 2048);
    gload_lds16(ksrc + 64 * HIDDEN, kd + 4096);
    gload_lds16(ksrc + 96 * HIDDEN, kd + 6144);
  }

  for (int kt = 0; kt < 16; ++kt) {
    __syncthreads();  // drains own DMA (vmcnt0) -> K(kt) visible; buf swap safe
    const unsigned short* kb = &Ks[kt & 1][0];
    const unsigned short* vt = vtile + kt * 8192;
#pragma unroll
    for (int g = 0; g < 4; g++) {
      // V A-frags for this group: issued here, consumed after QK+exp2 (~450cy)
      u16x8 vp[4];
#pragma unroll
      for (int mtd = 0; mtd < 4; mtd++)
        vp[mtd] = *(const u16x8*)(vt + (g * 4 + mtd) * 512 + lane * 8);
      // K DMA for kt+1: issued after this tile's LAST V loads (vmcnt FIFO ->
      // PV's vp-wait, on older slots, never drains the younger DMA)
      if (g == 3 && kt < 15) {
        const unsigned short* ks = ksrc + (size_t)(kt + 1) * (128 * HIDDEN);
        unsigned short* kd = &Ks[(kt + 1) & 1][tid * 8];
        gload_lds16(ks, kd);
        gload_lds16(ks + 32 * HIDDEN, kd + 2048);
        gload_lds16(ks + 64 * HIDDEN, kd + 4096);
        gload_lds16(ks + 96 * HIDDEN, kd + 6144);
      }
      u32x4 P[2];
#pragma unroll
      for (int half = 0; half < 2; half++) {
        const int mt = 2 * g + half;
        const u16x8 kf0 = *(const u16x8*)&kb[mt * 1024 + krd0];
        const u16x8 kf1 = *(const u16x8*)&kb[mt * 1024 + krd1];
        f32x4 s0 = zero, s1 = zero;
        __builtin_amdgcn_s_setprio(1);
        s0 = __builtin_amdgcn_mfma_f32_16x16x32_bf16(
            __builtin_bit_cast(bf16x8, kf0), __builtin_bit_cast(bf16x8, qf[0][0]), s0, 0, 0, 0);
        s0 = __builtin_amdgcn_mfma_f32_16x16x32_bf16(
            __builtin_bit_cast(bf16x8, kf1), __builtin_bit_cast(bf16x8, qf[0][1]), s0, 0, 0, 0);
        s1 = __builtin_amdgcn_mfma_f32_16x16x32_bf16(
            __builtin_bit_cast(bf16x8, kf0), __builtin_bit_cast(bf16x8, qf[1][0]), s1, 0, 0, 0);
        s1 = __builtin_amdgcn_mfma_f32_16x16x32_bf16(
            __builtin_bit_cast(bf16x8, kf1), __builtin_bit_cast(bf16x8, qf[1][1]), s1, 0, 0, 0);
        __builtin_amdgcn_s_setprio(0);
        float e0[4], e1[4];
#pragma unroll
        for (int r = 0; r < 4; r++) {
          e0[r] = __builtin_exp2f(s0[r]);
          e1[r] = __builtin_exp2f(s1[r]);
        }
        if (half == 0) {
          P[0][0] = pk2(e0[0], e0[1]); P[0][1] = pk2(e0[2], e0[3]);
          P[1][0] = pk2(e1[0], e1[1]); P[1][1] = pk2(e1[2], e1[3]);
        } else {
          P[0][2] = pk2(e0[0], e0[1]); P[0][3] = pk2(e0[2], e0[3]);
          P[1][2] = pk2(e1[0], e1[1]); P[1][3] = pk2(e1[2], e1[3]);
        }
      }
      // PV + denominator for this 32-key group
      __builtin_amdgcn_s_setprio(1);
#pragma unroll
      for (int nt = 0; nt < 2; nt++) {
        bf16x8 pb = __builtin_bit_cast(bf16x8, P[nt]);
        l2[nt] = __builtin_amdgcn_mfma_f32_16x16x32_bf16(
            __builtin_bit_cast(bf16x8, onesf), pb, l2[nt], 0, 0, 0);
#pragma unroll
        for (int mtd = 0; mtd < 4; mtd++)
          o[mtd][nt] = __builtin_amdgcn_mfma_f32_16x16x32_bf16(
              __builtin_bit_cast(bf16x8, vp[mtd]), pb, o[mtd][nt], 0, 0, 0);
      }
      __builtin_amdgcn_s_setprio(0);
    }
  }

  // l2[nt] rows are all identical = full denominator for q-column ln
  float inv[2];
#pragma unroll
  for (int nt = 0; nt < 2; nt++) inv[nt] = 1.0f / l2[nt][0];

#pragma unroll
  for (int nt = 0; nt < 2; nt++) {
    unsigned short* dst = X + (size_t)(b * SEQ + qw + nt * 16 + ln) * HIDDEN + h * HDIM;
#pragma unroll
    for (int mtd = 0; mtd < 4; mtd++) {
      s16x4 ov = pack4_bf16(o[mtd][nt][0] * inv[nt], o[mtd][nt][1] * inv[nt],
                            o[mtd][nt][2] * inv[nt], o[mtd][nt][3] * inv[nt]);
      *(s16x4*)(dst + mtd * 16 + quad * 4) = ov;
    }
  }
}

// ---------------------------------------------------------------------------
extern "C" void kernel_launch(void* const* d_in, const int* in_sizes, int n_in,
                              void* d_out, int out_size, void* d_ws, size_t ws_size,
                              hipStream_t stream) {
  const float* q_in = (const float*)d_in[0];
  const float* k_in = (const float*)d_in[1];
  const float* v_in = (const float*)d_in[2];
  const float* wq = (const float*)d_in[3];
  const float* bq = (const float*)d_in[4];
  const float* wk = (const float*)d_in[5];
  const float* bk = (const float*)d_in[6];
  const float* wv = (const float*)d_in[7];
  const float* bv = (const float*)d_in[8];
  const float* wf = (const float*)d_in[9];
  const float* bfb = (const float*)d_in[10];

  const size_t NX = (size_t)MTOT * HIDDEN;
  const size_t NW = (size_t)HIDDEN * HIDDEN;
  unsigned short* A = (unsigned short*)d_ws;
  unsigned short* Bx = A + NX;
  unsigned short* C = Bx + NX;
  unsigned short* W4 = C + NX;
  unsigned short* Qb = W4 + 4 * NW;
  unsigned short* Kb = Qb + NX;
  unsigned short* Vb = Kb + NX;

  cvt3<<<dim3(NX / 1024, 3), 256, 0, stream>>>(q_in, k_in, v_in, A, (int)NX);
  cvt4<<<dim3(NW / 1024, 4), 256, 0, stream>>>(wq, wk, wv, wf, W4, (int)NW);

  gemm_qkv<<<dim3(24, MTOT / 128), 256, 0, stream>>>(A, Bx, C, W4, bq, bk, bv, Qb, Kb, Vb);
  transpose_v<<<1024, 256, 0, stream>>>(Vb, Bx);
  attn8<<<dim3(NHEADS * 4, SEQ / 128), 256, 0, stream>>>(Qb, Kb, Bx, C);
  gemm_f<<<dim3(8, MTOT / 128), 256, 0, stream>>>(C, W4 + 3 * NW, bfb, (float*)d_out);
}

// Round 4
// 364.278 us; speedup vs baseline: 1.1840x; 1.0151x over previous
//
#include <hip/hip_runtime.h>
#include <stdint.h>

#define SEQ 2048
#define HIDDEN 1024
#define NHEADS 16
#define HDIM 64
#define MTOT 8192  // B*SEQ

// 1/sqrt(HDIM) * log2(e), folded into wq/bq so attn does exp2(S) directly
#define C1SCALE 0.1803368801111437f

typedef __bf16 bf16x8 __attribute__((ext_vector_type(8)));
typedef unsigned short u16x8 __attribute__((ext_vector_type(8)));
typedef short s16x4 __attribute__((ext_vector_type(4)));
typedef unsigned int u32x4 __attribute__((ext_vector_type(4)));
typedef float f32x4 __attribute__((ext_vector_type(4)));

#define GAS __attribute__((address_space(1)))
#define LAS __attribute__((address_space(3)))

__device__ __forceinline__ unsigned short bf16_rne(float f) {
  union { float f; unsigned int u; } v; v.f = f;
  return (unsigned short)((v.u + 0x7fffu + ((v.u >> 16) & 1u)) >> 16);
}

// pack 2 f32 -> 2 bf16 (RNE) in one dword via v_cvt_pk_bf16_f32 (T12 recipe;
// no builtin on gfx950). D[15:0]=bf16(lo), D[31:16]=bf16(hi).
__device__ __forceinline__ unsigned int pkcvt(float lo, float hi) {
  unsigned int r;
  asm("v_cvt_pk_bf16_f32 %0, %1, %2" : "=v"(r) : "v"(lo), "v"(hi));
  return r;
}

__device__ __forceinline__ void gload_lds16(const unsigned short* g, unsigned short* l) {
  __builtin_amdgcn_global_load_lds((GAS void*)(unsigned short*)g, (LAS void*)l, 16, 0, 0);
}

// ---------------- fused fp32 -> bf16 conversions ---------------------------
__global__ __launch_bounds__(256) void cvt3(const float* __restrict__ a,
                                            const float* __restrict__ b,
                                            const float* __restrict__ c,
                                            unsigned short* __restrict__ out,
                                            int perSeg) {
  const int seg = blockIdx.y;
  const float* in = seg == 0 ? a : (seg == 1 ? b : c);
  int i = blockIdx.x * 256 + threadIdx.x;
  float4 v = ((const float4*)in)[i];
  ushort4 o;
  o.x = bf16_rne(v.x); o.y = bf16_rne(v.y);
  o.z = bf16_rne(v.z); o.w = bf16_rne(v.w);
  ((ushort4*)(out + (size_t)seg * perSeg))[i] = o;
}

// seg 0 (wq) is pre-scaled by C1SCALE (softmax scale folded into Q projection)
__global__ __launch_bounds__(256) void cvt4(const float* __restrict__ a,
                                            const float* __restrict__ b,
                                            const float* __restrict__ c,
                                            const float* __restrict__ d,
                                            unsigned short* __restrict__ out,
                                            int perSeg) {
  const int seg = blockIdx.y;
  const float* in = seg == 0 ? a : (seg == 1 ? b : (seg == 2 ? c : d));
  const float sc = (seg == 0) ? C1SCALE : 1.0f;
  int i = blockIdx.x * 256 + threadIdx.x;
  float4 v = ((const float4*)in)[i];
  ushort4 o;
  o.x = bf16_rne(v.x * sc); o.y = bf16_rne(v.y * sc);
  o.z = bf16_rne(v.z * sc); o.w = bf16_rne(v.w * sc);
  ((ushort4*)(out + (size_t)seg * perSeg))[i] = o;
}

// ---------------- fused QKV GEMM -------------------------------------------
// XCD-aware bijective swizzle (nwg=1536, 1536%8==0): same-XCD blocks cover
// 192 consecutive work-ids = 8 m-panels x 24 n -> A-panels L2-resident.
// seg==2 (V) epilogue writes the attn PV fragment-linear Vt layout DIRECTLY
// (kills the transpose_v kernel): thread pair (acc[2p][ni], acc[2p+1][ni])
// is exactly one u16x8 at Vt[t*8192 + f*512 + lane*8], f=(wm*2+p)*4+ni,
// t=((b*16+h)*16+kt). Coalesced 1KiB wave stores.
__global__ __launch_bounds__(256) void gemm_qkv(const unsigned short* __restrict__ Xq,
                                                const unsigned short* __restrict__ Xk,
                                                const unsigned short* __restrict__ Xv,
                                                const unsigned short* __restrict__ W,
                                                const float* __restrict__ bq,
                                                const float* __restrict__ bk,
                                                const float* __restrict__ bv,
                                                unsigned short* __restrict__ Qb,
                                                unsigned short* __restrict__ Kb,
                                                unsigned short* __restrict__ Vt) {
  __shared__ unsigned short As[128 * 32];
  __shared__ unsigned short Bs[128 * 32];
  const int tid = threadIdx.x;
  const int lane = tid & 63, w = tid >> 6;
  const int quad = lane >> 4, ln = lane & 15;
  const int wm = w & 1, wn = w >> 1;
  // XCD swizzle: flat dispatch id -> contiguous work chunk per XCD
  const int flat = blockIdx.y * 24 + blockIdx.x;
  const int wid = (flat & 7) * 192 + (flat >> 3);
  const int mIdx = wid / 24, nIdx = wid % 24;
  const int mBase = mIdx * 128, nBase = (nIdx & 7) * 128;
  const int seg = nIdx >> 3;
  const unsigned short* A = seg == 0 ? Xq : (seg == 1 ? Xk : Xv);
  const float* bias = seg == 0 ? bq : (seg == 1 ? bk : bv);
  const float bscale = seg == 0 ? C1SCALE : 1.0f;
  const int K = HIDDEN;

  f32x4 acc[4][4];
  f32x4 zero = {0.f, 0.f, 0.f, 0.f};
#pragma unroll
  for (int i = 0; i < 4; i++)
#pragma unroll
    for (int j = 0; j < 4; j++) acc[i][j] = zero;

  const int e0 = tid * 8;
  const int e1 = (256 + tid) * 8;
  const int r0 = e0 >> 5, c0 = e0 & 31;
  const int r1 = e1 >> 5, c1 = e1 & 31;
  const unsigned short* Ap0 = A + (size_t)(mBase + r0) * K + c0;
  const unsigned short* Ap1 = A + (size_t)(mBase + r1) * K + c1;
  const unsigned short* Wp0 = W + (size_t)(seg * HIDDEN + nBase + r0) * K + c0;
  const unsigned short* Wp1 = W + (size_t)(seg * HIDDEN + nBase + r1) * K + c1;

  for (int k0 = 0; k0 < K; k0 += 32) {
    gload_lds16(Ap0 + k0, &As[e0]);
    gload_lds16(Ap1 + k0, &As[e1]);
    gload_lds16(Wp0 + k0, &Bs[e0]);
    gload_lds16(Wp1 + k0, &Bs[e1]);
    __syncthreads();
    u16x8 af[4], bfr[4];
#pragma unroll
    for (int mi = 0; mi < 4; mi++)
      af[mi] = *(const u16x8*)&As[(wm * 64 + mi * 16 + ln) * 32 + quad * 8];
#pragma unroll
    for (int ni = 0; ni < 4; ni++)
      bfr[ni] = *(const u16x8*)&Bs[(wn * 64 + ni * 16 + ln) * 32 + quad * 8];
#pragma unroll
    for (int mi = 0; mi < 4; mi++)
#pragma unroll
      for (int ni = 0; ni < 4; ni++)
        acc[mi][ni] = __builtin_amdgcn_mfma_f32_16x16x32_bf16(
            __builtin_bit_cast(bf16x8, af[mi]), __builtin_bit_cast(bf16x8, bfr[ni]),
            acc[mi][ni], 0, 0, 0);
    __syncthreads();
  }

  if (seg < 2) {
    unsigned short* outp = seg == 0 ? Qb : Kb;
#pragma unroll
    for (int ni = 0; ni < 4; ni++) {
      const int col = nBase + wn * 64 + ni * 16 + ln;
      const float bvv = bias[col] * bscale;
#pragma unroll
      for (int mi = 0; mi < 4; mi++) {
        const int row = mBase + wm * 64 + mi * 16 + quad * 4;
#pragma unroll
        for (int r = 0; r < 4; r++)
          outp[(size_t)(row + r) * HIDDEN + col] = bf16_rne(acc[mi][ni][r] + bvv);
      }
    }
  } else {
    // fused Vt epilogue (fragment-linear, PV-permuted)
    const int b = mBase >> 11;
    const int kt = (mBase & 2047) >> 7;
    const int h = (nBase >> 6) + wn;
    unsigned short* tb = Vt + (((size_t)(b * NHEADS + h) * 16 + kt) * 8192) + lane * 8;
#pragma unroll
    for (int ni = 0; ni < 4; ni++) {
      const int col = nBase + wn * 64 + ni * 16 + ln;
      const float bvv = bias[col];
#pragma unroll
      for (int p = 0; p < 2; p++) {
        const int f = (wm * 2 + p) * 4 + ni;
        u32x4 ov;
        ov[0] = pkcvt(acc[2 * p][ni][0] + bvv, acc[2 * p][ni][1] + bvv);
        ov[1] = pkcvt(acc[2 * p][ni][2] + bvv, acc[2 * p][ni][3] + bvv);
        ov[2] = pkcvt(acc[2 * p + 1][ni][0] + bvv, acc[2 * p + 1][ni][1] + bvv);
        ov[3] = pkcvt(acc[2 * p + 1][ni][2] + bvv, acc[2 * p + 1][ni][3] + bvv);
        *(u32x4*)(tb + f * 512) = ov;
      }
    }
  }
}

// ---------------- final GEMM (fp32 out) ------------------------------------
__global__ __launch_bounds__(256) void gemm_f(const unsigned short* __restrict__ A,
                                              const unsigned short* __restrict__ W,
                                              const float* __restrict__ bias,
                                              float* __restrict__ Cv) {
  __shared__ unsigned short As[128 * 32];
  __shared__ unsigned short Bs[128 * 32];
  const int tid = threadIdx.x;
  const int lane = tid & 63, w = tid >> 6;
  const int quad = lane >> 4, ln = lane & 15;
  const int wm = w & 1, wn = w >> 1;
  // XCD swizzle (nwg=512, 512%8==0): 64 consecutive work-ids per XCD
  const int flat = blockIdx.y * 8 + blockIdx.x;
  const int wid = (flat & 7) * 64 + (flat >> 3);
  const int mBase = (wid >> 3) * 128, nBase = (wid & 7) * 128;
  const int K = HIDDEN, N = HIDDEN;

  f32x4 acc[4][4];
  f32x4 zero = {0.f, 0.f, 0.f, 0.f};
#pragma unroll
  for (int i = 0; i < 4; i++)
#pragma unroll
    for (int j = 0; j < 4; j++) acc[i][j] = zero;

  const int e0 = tid * 8;
  const int e1 = (256 + tid) * 8;
  const int r0 = e0 >> 5, c0 = e0 & 31;
  const int r1 = e1 >> 5, c1 = e1 & 31;
  const unsigned short* Ap0 = A + (size_t)(mBase + r0) * K + c0;
  const unsigned short* Ap1 = A + (size_t)(mBase + r1) * K + c1;
  const unsigned short* Wp0 = W + (size_t)(nBase + r0) * K + c0;
  const unsigned short* Wp1 = W + (size_t)(nBase + r1) * K + c1;

  for (int k0 = 0; k0 < K; k0 += 32) {
    gload_lds16(Ap0 + k0, &As[e0]);
    gload_lds16(Ap1 + k0, &As[e1]);
    gload_lds16(Wp0 + k0, &Bs[e0]);
    gload_lds16(Wp1 + k0, &Bs[e1]);
    __syncthreads();
    u16x8 af[4], bfr[4];
#pragma unroll
    for (int mi = 0; mi < 4; mi++)
      af[mi] = *(const u16x8*)&As[(wm * 64 + mi * 16 + ln) * 32 + quad * 8];
#pragma unroll
    for (int ni = 0; ni < 4; ni++)
      bfr[ni] = *(const u16x8*)&Bs[(wn * 64 + ni * 16 + ln) * 32 + quad * 8];
#pragma unroll
    for (int mi = 0; mi < 4; mi++)
#pragma unroll
      for (int ni = 0; ni < 4; ni++)
        acc[mi][ni] = __builtin_amdgcn_mfma_f32_16x16x32_bf16(
            __builtin_bit_cast(bf16x8, af[mi]), __builtin_bit_cast(bf16x8, bfr[ni]),
            acc[mi][ni], 0, 0, 0);
    __syncthreads();
  }

#pragma unroll
  for (int ni = 0; ni < 4; ni++) {
    const int col = nBase + wn * 64 + ni * 16 + ln;
    const float bvv = bias[col];
#pragma unroll
    for (int mi = 0; mi < 4; mi++) {
      const int row = mBase + wm * 64 + mi * 16 + quad * 4;
#pragma unroll
      for (int r = 0; r < 4; r++)
        Cv[(size_t)(row + r) * N + col] = acc[mi][ni][r] + bvv;
    }
  }
}

// ---------------- flash attention v9: LDS-staged K, single-buffer reg V ----
// Structure as v8 (110us, MfmaUtil 30 + VALUBusy 68 = issue-saturated).
// v9 cuts VALU inst count: P packing via v_cvt_pk_bf16_f32 (1 inst/pair vs
// 3 for add+add+perm) -> -64 VALU inst/kt/wave; epilogue pack likewise.
// K path: 16KB tile DMA'd via global_load_lds, double-buffered, XOR-swizzled
// on the global source (rule #21), 1 barrier/kt. V: fragment-linear Vt (now
// produced directly by gemm_qkv), single vp[4] loaded at group top (~450cy
// issue-to-use covers L2). vmcnt FIFO: kt+1 DMA issued at g=3 after that
// group's V loads, so PV's vp-wait never drains the DMA; only the barrier
// does (a full phase later).
__global__ __launch_bounds__(256, 4) void attn9(const unsigned short* __restrict__ Q,
                                                const unsigned short* __restrict__ K,
                                                const unsigned short* __restrict__ Vt,
                                                unsigned short* __restrict__ X) {
  __shared__ unsigned short Ks[2][128 * 64];  // 2 x 16 KB, XOR-swizzled content
  const int tid = threadIdx.x, lane = tid & 63, w = tid >> 6;
  const int quad = lane >> 4, ln = lane & 15;
  const int bh = blockIdx.x, b = bh >> 4, h = bh & 15;
  const size_t base = (size_t)b * SEQ * HIDDEN + (size_t)h * HDIM;
  const unsigned short* Qh = Q + base;
  const unsigned short* Kh = K + base;
  const unsigned short* vtile = Vt + (size_t)bh * 16 * 8192;
  const int qw = blockIdx.y * 128 + w * 32;

  // K DMA: thread covers 16B chunks {tid + s*256}, s=0..3. chunk c: row=c>>3,
  // cb=c&7. LDS dest = linear c*16B (lane-linear per wave, as HW requires);
  // global source chunk = cb ^ (row&7)  (row&7 invariant across shots).
  const int kr0 = tid >> 3, kcb = tid & 7;
  const unsigned short* ksrc = Kh + (size_t)kr0 * HIDDEN + ((kcb ^ (kr0 & 7)) * 8);

  // swizzled K fragment read offsets (elems): row = mt*16+ln, chunk kk*4+quad
  const int krd0 = ln * 64 + ((quad ^ (ln & 7)) * 8);        // kk=0
  const int krd1 = ln * 64 + (((4 | quad) ^ (ln & 7)) * 8);  // kk=1

  // resident Q B-frags: B[k=d=kk2*32+quad*8+j][n=q=nt*16+ln]
  u16x8 qf[2][2];
#pragma unroll
  for (int nt = 0; nt < 2; nt++)
#pragma unroll
    for (int kk2 = 0; kk2 < 2; kk2++)
      qf[nt][kk2] = *(const u16x8*)(Qh + (size_t)(qw + nt * 16 + ln) * HIDDEN + kk2 * 32 + quad * 8);

  f32x4 o[4][2];
  f32x4 zero = {0.f, 0.f, 0.f, 0.f};
#pragma unroll
  for (int mtd = 0; mtd < 4; mtd++)
#pragma unroll
    for (int nt = 0; nt < 2; nt++) o[mtd][nt] = zero;
  f32x4 l2[2] = {zero, zero};

  u16x8 onesf;
#pragma unroll
  for (int j = 0; j < 8; j++) onesf[j] = 0x3F80;  // bf16 1.0

  // prologue: stage K(0) into buf0
  {
    unsigned short* kd = &Ks[0][tid * 8];
    gload_lds16(ksrc, kd);
    gload_lds16(ksrc + 32 * HIDDEN, kd + 2048);
    gload_lds16(ksrc + 64 * HIDDEN, kd + 4096);
    gload_lds16(ksrc + 96 * HIDDEN, kd + 6144);
  }

  for (int kt = 0; kt < 16; ++kt) {
    __syncthreads();  // drains own DMA (vmcnt0) -> K(kt) visible; buf swap safe
    const unsigned short* kb = &Ks[kt & 1][0];
    const unsigned short* vt = vtile + kt * 8192;
#pragma unroll
    for (int g = 0; g < 4; g++) {
      // V A-frags for this group: issued here, consumed after QK+exp2 (~450cy)
      u16x8 vp[4];
#pragma unroll
      for (int mtd = 0; mtd < 4; mtd++)
        vp[mtd] = *(const u16x8*)(vt + (g * 4 + mtd) * 512 + lane * 8);
      // K DMA for kt+1: issued after this tile's LAST V loads (vmcnt FIFO ->
      // PV's vp-wait, on older slots, never drains the younger DMA)
      if (g == 3 && kt < 15) {
        const unsigned short* ks = ksrc + (size_t)(kt + 1) * (128 * HIDDEN);
        unsigned short* kd = &Ks[(kt + 1) & 1][tid * 8];
        gload_lds16(ks, kd);
        gload_lds16(ks + 32 * HIDDEN, kd + 2048);
        gload_lds16(ks + 64 * HIDDEN, kd + 4096);
        gload_lds16(ks + 96 * HIDDEN, kd + 6144);
      }
      u32x4 P[2];
#pragma unroll
      for (int half = 0; half < 2; half++) {
        const int mt = 2 * g + half;
        const u16x8 kf0 = *(const u16x8*)&kb[mt * 1024 + krd0];
        const u16x8 kf1 = *(const u16x8*)&kb[mt * 1024 + krd1];
        f32x4 s0 = zero, s1 = zero;
        __builtin_amdgcn_s_setprio(1);
        s0 = __builtin_amdgcn_mfma_f32_16x16x32_bf16(
            __builtin_bit_cast(bf16x8, kf0), __builtin_bit_cast(bf16x8, qf[0][0]), s0, 0, 0, 0);
        s0 = __builtin_amdgcn_mfma_f32_16x16x32_bf16(
            __builtin_bit_cast(bf16x8, kf1), __builtin_bit_cast(bf16x8, qf[0][1]), s0, 0, 0, 0);
        s1 = __builtin_amdgcn_mfma_f32_16x16x32_bf16(
            __builtin_bit_cast(bf16x8, kf0), __builtin_bit_cast(bf16x8, qf[1][0]), s1, 0, 0, 0);
        s1 = __builtin_amdgcn_mfma_f32_16x16x32_bf16(
            __builtin_bit_cast(bf16x8, kf1), __builtin_bit_cast(bf16x8, qf[1][1]), s1, 0, 0, 0);
        __builtin_amdgcn_s_setprio(0);
        float e0[4], e1[4];
#pragma unroll
        for (int r = 0; r < 4; r++) {
          e0[r] = __builtin_exp2f(s0[r]);
          e1[r] = __builtin_exp2f(s1[r]);
        }
        if (half == 0) {
          P[0][0] = pkcvt(e0[0], e0[1]); P[0][1] = pkcvt(e0[2], e0[3]);
          P[1][0] = pkcvt(e1[0], e1[1]); P[1][1] = pkcvt(e1[2], e1[3]);
        } else {
          P[0][2] = pkcvt(e0[0], e0[1]); P[0][3] = pkcvt(e0[2], e0[3]);
          P[1][2] = pkcvt(e1[0], e1[1]); P[1][3] = pkcvt(e1[2], e1[3]);
        }
      }
      // PV + denominator for this 32-key group
      __builtin_amdgcn_s_setprio(1);
#pragma unroll
      for (int nt = 0; nt < 2; nt++) {
        bf16x8 pb = __builtin_bit_cast(bf16x8, P[nt]);
        l2[nt] = __builtin_amdgcn_mfma_f32_16x16x32_bf16(
            __builtin_bit_cast(bf16x8, onesf), pb, l2[nt], 0, 0, 0);
#pragma unroll
        for (int mtd = 0; mtd < 4; mtd++)
          o[mtd][nt] = __builtin_amdgcn_mfma_f32_16x16x32_bf16(
              __builtin_bit_cast(bf16x8, vp[mtd]), pb, o[mtd][nt], 0, 0, 0);
      }
      __builtin_amdgcn_s_setprio(0);
    }
  }

  // l2[nt] rows are all identical = full denominator for q-column ln
  float inv[2];
#pragma unroll
  for (int nt = 0; nt < 2; nt++) inv[nt] = 1.0f / l2[nt][0];

#pragma unroll
  for (int nt = 0; nt < 2; nt++) {
    unsigned short* dst = X + (size_t)(b * SEQ + qw + nt * 16 + ln) * HIDDEN + h * HDIM;
#pragma unroll
    for (int mtd = 0; mtd < 4; mtd++) {
      uint2 ov;
      ov.x = pkcvt(o[mtd][nt][0] * inv[nt], o[mtd][nt][1] * inv[nt]);
      ov.y = pkcvt(o[mtd][nt][2] * inv[nt], o[mtd][nt][3] * inv[nt]);
      *(uint2*)(dst + mtd * 16 + quad * 4) = ov;
    }
  }
}

// ---------------------------------------------------------------------------
extern "C" void kernel_launch(void* const* d_in, const int* in_sizes, int n_in,
                              void* d_out, int out_size, void* d_ws, size_t ws_size,
                              hipStream_t stream) {
  const float* q_in = (const float*)d_in[0];
  const float* k_in = (const float*)d_in[1];
  const float* v_in = (const float*)d_in[2];
  const float* wq = (const float*)d_in[3];
  const float* bq = (const float*)d_in[4];
  const float* wk = (const float*)d_in[5];
  const float* bk = (const float*)d_in[6];
  const float* wv = (const float*)d_in[7];
  const float* bv = (const float*)d_in[8];
  const float* wf = (const float*)d_in[9];
  const float* bfb = (const float*)d_in[10];

  const size_t NX = (size_t)MTOT * HIDDEN;
  const size_t NW = (size_t)HIDDEN * HIDDEN;
  unsigned short* A = (unsigned short*)d_ws;
  unsigned short* Bx = A + NX;
  unsigned short* C = Bx + NX;
  unsigned short* W4 = C + NX;
  unsigned short* Qb = W4 + 4 * NW;
  unsigned short* Kb = Qb + NX;
  unsigned short* Vtb = Kb + NX;  // fragment-linear Vt (written by gemm_qkv)

  cvt3<<<dim3(NX / 1024, 3), 256, 0, stream>>>(q_in, k_in, v_in, A, (int)NX);
  cvt4<<<dim3(NW / 1024, 4), 256, 0, stream>>>(wq, wk, wv, wf, W4, (int)NW);

  gemm_qkv<<<dim3(24, MTOT / 128), 256, 0, stream>>>(A, Bx, C, W4, bq, bk, bv, Qb, Kb, Vtb);
  attn9<<<dim3(NHEADS * 4, SEQ / 128), 256, 0, stream>>>(Qb, Kb, Vtb, C);
  gemm_f<<<dim3(8, MTOT / 128), 256, 0, stream>>>(C, W4 + 3 * NW, bfb, (float*)d_out);
}